// Round 1
// baseline (3412.949 us; speedup 1.0000x reference)
//
#include <hip/hip_runtime.h>
#include <math.h>

#define B_      4
#define C_      256
#define NTOK    4096
#define GROUPS_ 32
#define CPG_    8
#define EPS_    1e-6f
#define SCALE_  0.0625f   // 1/sqrt(256)

// ---------------------------------------------------------------------------
// GroupNorm: one block per (batch, group). 8 channels x 4096 spatial = 32768.
// ---------------------------------------------------------------------------
__global__ __launch_bounds__(256) void gn_kernel(
    const float* __restrict__ x, const float* __restrict__ gamma,
    const float* __restrict__ beta, float* __restrict__ h) {
  const int b = blockIdx.x / GROUPS_;
  const int g = blockIdx.x % GROUPS_;
  const size_t base = ((size_t)b * C_ + (size_t)g * CPG_) * NTOK;
  const float* xp = x + base;
  float* hp = h + base;
  const int t = threadIdx.x;
  const int CNT = CPG_ * NTOK;  // 32768

  float s = 0.f, s2 = 0.f;
  for (int i = t * 4; i < CNT; i += 1024) {
    float4 v = *reinterpret_cast<const float4*>(xp + i);
    s  += v.x + v.y + v.z + v.w;
    s2 += v.x * v.x + v.y * v.y + v.z * v.z + v.w * v.w;
  }
  #pragma unroll
  for (int m = 32; m >= 1; m >>= 1) {
    s  += __shfl_xor(s, m);
    s2 += __shfl_xor(s2, m);
  }
  __shared__ float red[8];
  __shared__ float stats[2];
  const int wv = t >> 6;
  if ((t & 63) == 0) { red[wv] = s; red[4 + wv] = s2; }
  __syncthreads();
  if (t == 0) {
    float ts  = red[0] + red[1] + red[2] + red[3];
    float ts2 = red[4] + red[5] + red[6] + red[7];
    float mu  = ts / (float)CNT;
    float var = ts2 / (float)CNT - mu * mu;
    stats[0] = mu;
    stats[1] = rsqrtf(var + EPS_);
  }
  __syncthreads();
  const float mu = stats[0], inv = stats[1];
  for (int i = t * 4; i < CNT; i += 1024) {
    float4 v = *reinterpret_cast<const float4*>(xp + i);
    const int c = g * CPG_ + (i >> 12);  // i / 4096
    const float ga = gamma[c] * inv;
    const float be = beta[c] - mu * ga;
    v.x = v.x * ga + be;
    v.y = v.y * ga + be;
    v.z = v.z * ga + be;
    v.w = v.w * ga + be;
    *reinterpret_cast<float4*>(hp + i) = v;
  }
}

// ---------------------------------------------------------------------------
// 1x1-conv GEMM: Out[b][m][n] = bias[m] + sum_c Wt[m][c] * Hin[b][c][n]
//               (+ Res[b][m][n] if RES). Tile 64x64, BK=16, 256 thr, 4x4/thr.
// ---------------------------------------------------------------------------
template <int RES>
__global__ __launch_bounds__(256) void nin_gemm(
    const float* __restrict__ Wt, const float* __restrict__ bias,
    const float* __restrict__ Hin, const float* __restrict__ Res,
    float* __restrict__ Out) {
  const int b  = blockIdx.z;
  const int n0 = blockIdx.x * 64;
  const int m0 = blockIdx.y * 64;
  const float* Hb = Hin + (size_t)b * C_ * NTOK;

  __shared__ float Ws[16][68];
  __shared__ float Hs[16][68];

  const int t  = threadIdx.x;
  const int tm = t >> 4;   // 0..15
  const int tn = t & 15;   // 0..15

  float acc[4][4];
  #pragma unroll
  for (int i = 0; i < 4; ++i)
    #pragma unroll
    for (int j = 0; j < 4; ++j) acc[i][j] = 0.f;

  for (int k0 = 0; k0 < C_; k0 += 16) {
    __syncthreads();
    {  // W tile: Ws[k][m] = Wt[(m0+m)*C + k0+k]
      const int m  = t >> 2;
      const int kq = (t & 3) * 4;
      float4 w4 = *reinterpret_cast<const float4*>(
          Wt + (size_t)(m0 + m) * C_ + k0 + kq);
      Ws[kq + 0][m] = w4.x;
      Ws[kq + 1][m] = w4.y;
      Ws[kq + 2][m] = w4.z;
      Ws[kq + 3][m] = w4.w;
    }
    {  // H tile: Hs[k][n] = Hb[(k0+k)*N + n0+n]
      const int kk = t >> 4;
      const int nq = (t & 15) * 4;
      *reinterpret_cast<float4*>(&Hs[kk][nq]) =
          *reinterpret_cast<const float4*>(Hb + (size_t)(k0 + kk) * NTOK + n0 + nq);
    }
    __syncthreads();
    #pragma unroll
    for (int k = 0; k < 16; ++k) {
      const float4 a4 = *reinterpret_cast<const float4*>(&Ws[k][tm * 4]);
      const float4 b4 = *reinterpret_cast<const float4*>(&Hs[k][tn * 4]);
      acc[0][0] += a4.x * b4.x; acc[0][1] += a4.x * b4.y; acc[0][2] += a4.x * b4.z; acc[0][3] += a4.x * b4.w;
      acc[1][0] += a4.y * b4.x; acc[1][1] += a4.y * b4.y; acc[1][2] += a4.y * b4.z; acc[1][3] += a4.y * b4.w;
      acc[2][0] += a4.z * b4.x; acc[2][1] += a4.z * b4.y; acc[2][2] += a4.z * b4.z; acc[2][3] += a4.z * b4.w;
      acc[3][0] += a4.w * b4.x; acc[3][1] += a4.w * b4.y; acc[3][2] += a4.w * b4.z; acc[3][3] += a4.w * b4.w;
    }
  }
  #pragma unroll
  for (int i = 0; i < 4; ++i) {
    const int m = m0 + tm * 4 + i;
    const float bv = bias[m];
    const size_t off = ((size_t)b * C_ + m) * NTOK + n0 + tn * 4;
    float4 r;
    r.x = acc[i][0] + bv;
    r.y = acc[i][1] + bv;
    r.z = acc[i][2] + bv;
    r.w = acc[i][3] + bv;
    if (RES) {
      float4 x4 = *reinterpret_cast<const float4*>(Res + off);
      r.x += x4.x; r.y += x4.y; r.z += x4.z; r.w += x4.w;
    }
    *reinterpret_cast<float4*>(Out + off) = r;
  }
}

// ---------------------------------------------------------------------------
// Flash attention: block = 32 queries, loop key chunks of 128.
// S-phase: thread owns 4 q-rows x 4 m-cols. O-phase: thread owns 1 q x 32 c.
// ---------------------------------------------------------------------------
__global__ __launch_bounds__(256) void flash_kernel(
    const float* __restrict__ q, const float* __restrict__ k,
    const float* __restrict__ v, float* __restrict__ o) {
  const int b  = blockIdx.y;
  const int q0 = blockIdx.x * 32;
  const int t  = threadIdx.x;
  const size_t bb = (size_t)b * C_ * NTOK;

  __shared__ float Qs[32][257];   // [q][c]
  __shared__ float Ks[32][132];   // [ci][m]   row stride 528B = 33*16B
  __shared__ float Ps[32][136];   // [q][m]    row stride 544B = 34*16B
  __shared__ float Vs[256][36];   // [c][m]    row stride 144B = 9*16B
  __shared__ float alpha_s[32];
  __shared__ float lsum_s[32];

  // Load Q tile transposed into [q][c] (coalesced: 8 lanes per 128B row seg)
  #pragma unroll
  for (int j = 0; j < 8; ++j) {
    const int f4 = t + 256 * j;
    const int c  = f4 >> 3;
    const int qq = (f4 & 7) * 4;
    float4 v4 = *reinterpret_cast<const float4*>(q + bb + (size_t)c * NTOK + q0 + qq);
    Qs[qq + 0][c] = v4.x;
    Qs[qq + 1][c] = v4.y;
    Qs[qq + 2][c] = v4.z;
    Qs[qq + 3][c] = v4.w;
  }

  const int qb    = t >> 5;   // 0..7  (S-phase row group)
  const int mlane = t & 31;   // 0..31
  const int m4    = mlane * 4;
  const int q_o   = t & 31;   // O-phase query
  const int cb2   = t >> 5;   // O-phase channel block

  float m_run[4], l_run[4];
  #pragma unroll
  for (int r = 0; r < 4; ++r) { m_run[r] = -1e30f; l_run[r] = 0.f; }
  float Oacc[32];
  #pragma unroll
  for (int i = 0; i < 32; ++i) Oacc[i] = 0.f;

  for (int mm0 = 0; mm0 < NTOK; mm0 += 128) {
    float Sacc[4][4];
    #pragma unroll
    for (int r = 0; r < 4; ++r)
      #pragma unroll
      for (int jj = 0; jj < 4; ++jj) Sacc[r][jj] = 0.f;

    // ---- S = Q^T K over channel chunks of 32 ----
    for (int cc = 0; cc < C_; cc += 32) {
      __syncthreads();
      #pragma unroll
      for (int j = 0; j < 4; ++j) {
        const int f4 = t + 256 * j;
        const int ci = f4 >> 5;
        const int mq = (f4 & 31) * 4;
        *reinterpret_cast<float4*>(&Ks[ci][mq]) =
            *reinterpret_cast<const float4*>(k + bb + (size_t)(cc + ci) * NTOK + mm0 + mq);
      }
      __syncthreads();
      #pragma unroll
      for (int ci = 0; ci < 32; ++ci) {
        const float qv0 = Qs[qb +  0][cc + ci];
        const float qv1 = Qs[qb +  8][cc + ci];
        const float qv2 = Qs[qb + 16][cc + ci];
        const float qv3 = Qs[qb + 24][cc + ci];
        const float4 kv = *reinterpret_cast<const float4*>(&Ks[ci][m4]);
        Sacc[0][0] += qv0 * kv.x; Sacc[0][1] += qv0 * kv.y; Sacc[0][2] += qv0 * kv.z; Sacc[0][3] += qv0 * kv.w;
        Sacc[1][0] += qv1 * kv.x; Sacc[1][1] += qv1 * kv.y; Sacc[1][2] += qv1 * kv.z; Sacc[1][3] += qv1 * kv.w;
        Sacc[2][0] += qv2 * kv.x; Sacc[2][1] += qv2 * kv.y; Sacc[2][2] += qv2 * kv.z; Sacc[2][3] += qv2 * kv.w;
        Sacc[3][0] += qv3 * kv.x; Sacc[3][1] += qv3 * kv.y; Sacc[3][2] += qv3 * kv.z; Sacc[3][3] += qv3 * kv.w;
      }
    }

    // ---- online softmax over this chunk (rows live in 32-lane groups) ----
    float alpha_r[4];
    #pragma unroll
    for (int r = 0; r < 4; ++r) {
      #pragma unroll
      for (int jj = 0; jj < 4; ++jj) Sacc[r][jj] *= SCALE_;
      float mx = fmaxf(fmaxf(Sacc[r][0], Sacc[r][1]), fmaxf(Sacc[r][2], Sacc[r][3]));
      #pragma unroll
      for (int msk = 16; msk >= 1; msk >>= 1) mx = fmaxf(mx, __shfl_xor(mx, msk));
      const float mnew = fmaxf(m_run[r], mx);
      alpha_r[r] = __expf(m_run[r] - mnew);
      float ps = 0.f;
      #pragma unroll
      for (int jj = 0; jj < 4; ++jj) {
        const float p = __expf(Sacc[r][jj] - mnew);
        Sacc[r][jj] = p;
        ps += p;
      }
      #pragma unroll
      for (int msk = 16; msk >= 1; msk >>= 1) ps += __shfl_xor(ps, msk);
      l_run[r] = l_run[r] * alpha_r[r] + ps;
      m_run[r] = mnew;
    }
    __syncthreads();  // previous O-phase done reading Ps
    #pragma unroll
    for (int r = 0; r < 4; ++r)
      *reinterpret_cast<float4*>(&Ps[qb + 8 * r][m4]) =
          make_float4(Sacc[r][0], Sacc[r][1], Sacc[r][2], Sacc[r][3]);
    if (mlane == 0) {
      #pragma unroll
      for (int r = 0; r < 4; ++r) alpha_s[qb + 8 * r] = alpha_r[r];
    }
    __syncthreads();

    // ---- O update ----
    const float asc = alpha_s[q_o];
    #pragma unroll
    for (int i = 0; i < 32; ++i) Oacc[i] *= asc;

    for (int ms = 0; ms < 128; ms += 32) {
      __syncthreads();  // previous sub-chunk done reading Vs
      #pragma unroll
      for (int j = 0; j < 8; ++j) {
        const int f4 = t + 256 * j;
        const int c  = f4 >> 3;
        const int mq = (f4 & 7) * 4;
        *reinterpret_cast<float4*>(&Vs[c][mq]) =
            *reinterpret_cast<const float4*>(v + bb + (size_t)c * NTOK + mm0 + ms + mq);
      }
      __syncthreads();
      float pr[32];
      #pragma unroll
      for (int m8 = 0; m8 < 8; ++m8) {
        const float4 p4 = *reinterpret_cast<const float4*>(&Ps[q_o][ms + m8 * 4]);
        pr[m8 * 4 + 0] = p4.x;
        pr[m8 * 4 + 1] = p4.y;
        pr[m8 * 4 + 2] = p4.z;
        pr[m8 * 4 + 3] = p4.w;
      }
      #pragma unroll
      for (int i = 0; i < 32; ++i) {
        const int c = cb2 * 32 + i;
        #pragma unroll
        for (int m8 = 0; m8 < 8; ++m8) {
          const float4 v4 = *reinterpret_cast<const float4*>(&Vs[c][m8 * 4]);
          Oacc[i] += v4.x * pr[m8 * 4 + 0] + v4.y * pr[m8 * 4 + 1] +
                     v4.z * pr[m8 * 4 + 2] + v4.w * pr[m8 * 4 + 3];
        }
      }
    }
  }

  if (mlane == 0) {
    #pragma unroll
    for (int r = 0; r < 4; ++r) lsum_s[qb + 8 * r] = l_run[r];
  }
  __syncthreads();
  const float invl = 1.0f / lsum_s[q_o];
  #pragma unroll
  for (int i = 0; i < 32; ++i) {
    const int c = cb2 * 32 + i;
    o[bb + (size_t)c * NTOK + q0 + q_o] = Oacc[i] * invl;
  }
}

// ---------------------------------------------------------------------------
extern "C" void kernel_launch(void* const* d_in, const int* in_sizes, int n_in,
                              void* d_out, int out_size, void* d_ws, size_t ws_size,
                              hipStream_t stream) {
  (void)in_sizes; (void)n_in; (void)out_size; (void)ws_size;
  const float* x     = (const float*)d_in[0];
  const float* gamma = (const float*)d_in[1];
  const float* beta  = (const float*)d_in[2];
  const float* wq    = (const float*)d_in[3];
  const float* bq    = (const float*)d_in[4];
  const float* wk    = (const float*)d_in[5];
  const float* bk    = (const float*)d_in[6];
  const float* wv    = (const float*)d_in[7];
  const float* bv    = (const float*)d_in[8];
  const float* wo    = (const float*)d_in[9];
  const float* bo    = (const float*)d_in[10];
  float* out = (float*)d_out;
  float* ws  = (float*)d_ws;

  const size_t SZ = (size_t)B_ * C_ * NTOK;  // 4,194,304 floats = 16 MB
  float* hbuf = ws;            // [0, 16MB)   — reused as obuf after qkv
  float* qbuf = ws + SZ;       // [16, 32MB)
  float* kbuf = ws + 2 * SZ;   // [32, 48MB)
  float* vbuf = ws + 3 * SZ;   // [48, 64MB)  — total ws need: 64 MB
  float* obuf = hbuf;

  gn_kernel<<<dim3(B_ * GROUPS_), 256, 0, stream>>>(x, gamma, beta, hbuf);

  dim3 gg(NTOK / 64, C_ / 64, B_);
  nin_gemm<0><<<gg, 256, 0, stream>>>(wq, bq, hbuf, nullptr, qbuf);
  nin_gemm<0><<<gg, 256, 0, stream>>>(wk, bk, hbuf, nullptr, kbuf);
  nin_gemm<0><<<gg, 256, 0, stream>>>(wv, bv, hbuf, nullptr, vbuf);

  flash_kernel<<<dim3(NTOK / 32, B_), 256, 0, stream>>>(qbuf, kbuf, vbuf, obuf);

  nin_gemm<1><<<gg, 256, 0, stream>>>(wo, bo, obuf, x, out);
}

// Round 2
// 270.316 us; speedup vs baseline: 12.6258x; 12.6258x over previous
//
#include <hip/hip_runtime.h>
#include <math.h>

#define B_      4
#define C_      256
#define NTOK    4096
#define GROUPS_ 32
#define CPG_    8
#define EPS_    1e-6f
#define QSCALE  0.0625f   // 1/sqrt(256), folded into Q projection output

typedef __attribute__((ext_vector_type(8))) short short8v;    // 8 bf16 = 4 VGPR
typedef __attribute__((ext_vector_type(4))) float float4v;    // MFMA C/D
typedef __attribute__((ext_vector_type(4))) unsigned short ushort4v;
typedef unsigned short ushort_t;

__device__ __forceinline__ ushort_t f2bf(float f) {
  union { float f; unsigned u; } v; v.f = f;
  unsigned r = (v.u + 0x7FFFu + ((v.u >> 16) & 1u)) >> 16;  // RNE
  return (ushort_t)r;
}

__device__ __forceinline__ float4v mfma16(short8v a, short8v b, float4v c) {
  return __builtin_amdgcn_mfma_f32_16x16x32_bf16(a, b, c, 0, 0, 0);
}

// ---------------------------------------------------------------------------
// GN pass 1: per-(b,group) mean / rstd
// ---------------------------------------------------------------------------
__global__ __launch_bounds__(256) void gn_stats(const float* __restrict__ x,
                                                float* __restrict__ stats) {
  const int bg = blockIdx.x;  // b*32+g
  const size_t base = (size_t)bg * CPG_ * NTOK;
  const int t = threadIdx.x;
  float s = 0.f, s2 = 0.f;
  for (int i = t * 4; i < CPG_ * NTOK; i += 1024) {
    float4 v = *reinterpret_cast<const float4*>(x + base + i);
    s  += v.x + v.y + v.z + v.w;
    s2 += v.x * v.x + v.y * v.y + v.z * v.z + v.w * v.w;
  }
  #pragma unroll
  for (int m = 32; m >= 1; m >>= 1) { s += __shfl_xor(s, m); s2 += __shfl_xor(s2, m); }
  __shared__ float red[8];
  const int wv = t >> 6;
  if ((t & 63) == 0) { red[wv] = s; red[4 + wv] = s2; }
  __syncthreads();
  if (t == 0) {
    float ts  = red[0] + red[1] + red[2] + red[3];
    float ts2 = red[4] + red[5] + red[6] + red[7];
    const float inv_n = 1.0f / (float)(CPG_ * NTOK);
    float mu  = ts * inv_n;
    float var = ts2 * inv_n - mu * mu;
    stats[bg * 2]     = mu;
    stats[bg * 2 + 1] = rsqrtf(var + EPS_);
  }
}

// ---------------------------------------------------------------------------
// GN pass 2: normalize + affine, write Ht[b][n][c] bf16 (token-major)
// ---------------------------------------------------------------------------
__global__ __launch_bounds__(256) void gn_apply(
    const float* __restrict__ x, const float* __restrict__ gamma,
    const float* __restrict__ beta, const float* __restrict__ stats,
    ushort_t* __restrict__ Ht) {
  const int b  = blockIdx.y;
  const int n0 = blockIdx.x * 64;
  const int t  = threadIdx.x;
  __shared__ __align__(16) ushort_t Hs[64][264];
  const float* xb = x + (size_t)b * C_ * NTOK;
  #pragma unroll
  for (int it = 0; it < 16; ++it) {
    const int idx = t + 256 * it;        // 0..4095
    const int c   = idx >> 4;            // 0..255
    const int ch  = (idx & 15) * 4;      // n offset 0..60
    float4 v = *reinterpret_cast<const float4*>(xb + (size_t)c * NTOK + n0 + ch);
    const float mu = stats[(b * GROUPS_ + (c >> 3)) * 2];
    const float rs = stats[(b * GROUPS_ + (c >> 3)) * 2 + 1];
    const float ga = gamma[c] * rs;
    const float be = beta[c] - mu * ga;
    Hs[ch + 0][c] = f2bf(v.x * ga + be);
    Hs[ch + 1][c] = f2bf(v.y * ga + be);
    Hs[ch + 2][c] = f2bf(v.z * ga + be);
    Hs[ch + 3][c] = f2bf(v.w * ga + be);
  }
  __syncthreads();
  ushort_t* Hb = Ht + (size_t)b * NTOK * C_;
  #pragma unroll
  for (int it = 0; it < 8; ++it) {
    const int idx = t + 256 * it;        // 0..2047
    const int row = idx >> 5;
    const int ch  = (idx & 31) * 8;
    *reinterpret_cast<short8v*>(Hb + (size_t)(n0 + row) * C_ + ch) =
        *reinterpret_cast<const short8v*>(&Hs[row][ch]);
  }
}

// ---------------------------------------------------------------------------
// Convert the 4 weight matrices to bf16 (contiguous [4][256][256])
// ---------------------------------------------------------------------------
__global__ __launch_bounds__(256) void wconv(
    const float* __restrict__ wq, const float* __restrict__ wk,
    const float* __restrict__ wv, const float* __restrict__ wo,
    ushort_t* __restrict__ Wb) {
  const int m = blockIdx.y;
  const float* srcs[4] = {wq, wk, wv, wo};
  const float* s = srcs[m];
  const int i = (blockIdx.x * 256 + threadIdx.x) * 4;
  float4 v = *reinterpret_cast<const float4*>(s + i);
  ushort4v o4 = {f2bf(v.x), f2bf(v.y), f2bf(v.z), f2bf(v.w)};
  *reinterpret_cast<ushort4v*>(Wb + (size_t)m * 65536 + i) = o4;
}

// ---------------------------------------------------------------------------
// MFMA 1x1-conv GEMM: D[m][n] = sum_c W[m][c] * Ht[n][c]  (Ht token-major)
// MODE 0: bf16 out transposed [n][m], (acc+bias)*oscale   (Q, K)
// MODE 1: bf16 out natural [m][n]                          (V)
// MODE 2: f32 out natural [m][n] + bias + residual x       (final)
// Block: 256 thr = 4 waves; wave w owns m in [64w,64w+64); n-tile = 64.
// ---------------------------------------------------------------------------
template <int MODE>
__global__ __launch_bounds__(256) void nin_mfma(
    const ushort_t* __restrict__ Wb, const float* __restrict__ bias,
    const ushort_t* __restrict__ Hin, const float* __restrict__ xres,
    void* __restrict__ outp, float oscale) {
  const int b  = blockIdx.y;
  const int n0 = blockIdx.x * 64;
  const int t  = threadIdx.x;
  const int w  = t >> 6, l = t & 63;
  const int lg = l >> 4, ln = l & 15;
  __shared__ __align__(16) ushort_t Hs[64][264];
  const ushort_t* Hb = Hin + (size_t)b * NTOK * C_;
  #pragma unroll
  for (int it = 0; it < 8; ++it) {
    const int idx = t + 256 * it;
    const int row = idx >> 5;
    const int ch  = (idx & 31) * 8;
    *reinterpret_cast<short8v*>(&Hs[row][ch]) =
        *reinterpret_cast<const short8v*>(Hb + (size_t)(n0 + row) * C_ + ch);
  }
  __syncthreads();

  float4v acc[4][4];
  #pragma unroll
  for (int mt = 0; mt < 4; ++mt)
    #pragma unroll
    for (int nt = 0; nt < 4; ++nt) acc[mt][nt] = (float4v){0.f, 0.f, 0.f, 0.f};

  const ushort_t* Wrow = Wb + (size_t)(64 * w + ln) * C_;
  #pragma unroll
  for (int kk = 0; kk < 8; ++kk) {
    short8v af[4], bfr[4];
    #pragma unroll
    for (int mt = 0; mt < 4; ++mt)
      af[mt] = *reinterpret_cast<const short8v*>(Wrow + mt * 16 * C_ + kk * 32 + 8 * lg);
    #pragma unroll
    for (int nt = 0; nt < 4; ++nt)
      bfr[nt] = *reinterpret_cast<const short8v*>(&Hs[nt * 16 + ln][kk * 32 + 8 * lg]);
    #pragma unroll
    for (int mt = 0; mt < 4; ++mt)
      #pragma unroll
      for (int nt = 0; nt < 4; ++nt)
        acc[mt][nt] = mfma16(af[mt], bfr[nt], acc[mt][nt]);
  }

  #pragma unroll
  for (int mt = 0; mt < 4; ++mt) {
    const int mb = 64 * w + mt * 16 + 4 * lg;   // first of 4 consecutive m rows
    #pragma unroll
    for (int nt = 0; nt < 4; ++nt) {
      const int n = n0 + nt * 16 + ln;
      if (MODE == 0) {
        ushort4v pk;
        #pragma unroll
        for (int r = 0; r < 4; ++r)
          pk[r] = f2bf((acc[mt][nt][r] + bias[mb + r]) * oscale);
        *reinterpret_cast<ushort4v*>((ushort_t*)outp + ((size_t)b * NTOK + n) * C_ + mb) = pk;
      } else if (MODE == 1) {
        #pragma unroll
        for (int r = 0; r < 4; ++r)
          ((ushort_t*)outp)[((size_t)b * C_ + mb + r) * NTOK + n] =
              f2bf(acc[mt][nt][r] + bias[mb + r]);
      } else {
        #pragma unroll
        for (int r = 0; r < 4; ++r) {
          const size_t off = ((size_t)b * C_ + mb + r) * NTOK + n;
          ((float*)outp)[off] = acc[mt][nt][r] + bias[mb + r] + xres[off];
        }
      }
    }
  }
}

// ---------------------------------------------------------------------------
// MFMA flash attention. Block: 64 queries, 4 waves x 16 q. KBLK = 64.
// Qt,Kt: [b][n][c] bf16.  V: [b][c][n] bf16.  Ot: [b][n][c] bf16.
// ---------------------------------------------------------------------------
__global__ __launch_bounds__(256, 2) void flash_mfma(
    const ushort_t* __restrict__ Qt, const ushort_t* __restrict__ Kt,
    const ushort_t* __restrict__ V, ushort_t* __restrict__ Ot) {
  const int b  = blockIdx.y;
  const int q0 = blockIdx.x * 64;
  const int t  = threadIdx.x;
  const int w  = t >> 6, l = t & 63;
  const int lg = l >> 4, ln = l & 15;

  __shared__ __align__(16) ushort_t Ks[64][264];   // [key][c]  stride 528B
  __shared__ __align__(16) ushort_t Vs[256][72];   // [c][m]    stride 144B
  __shared__ __align__(16) ushort_t Ps[4][16][72]; // per-wave [q][m]

  const ushort_t* Qb = Qt + (size_t)b * NTOK * C_;
  const ushort_t* Kb = Kt + (size_t)b * NTOK * C_;
  const ushort_t* Vb = V  + (size_t)b * C_ * NTOK;
  ushort_t* Ob = Ot + (size_t)b * NTOK * C_;

  // Q fragments (A operand), resident for the whole block
  short8v qf[8];
  {
    const ushort_t* qrow = Qb + (size_t)(q0 + 16 * w + ln) * C_;
    #pragma unroll
    for (int kk = 0; kk < 8; ++kk)
      qf[kk] = *reinterpret_cast<const short8v*>(qrow + kk * 32 + 8 * lg);
  }

  float4v Oacc[16];
  #pragma unroll
  for (int ct = 0; ct < 16; ++ct) Oacc[ct] = (float4v){0.f, 0.f, 0.f, 0.f};
  float m_run[4], l_run[4];
  #pragma unroll
  for (int r = 0; r < 4; ++r) { m_run[r] = -1e30f; l_run[r] = 0.f; }

  for (int m0 = 0; m0 < NTOK; m0 += 64) {
    __syncthreads();  // everyone done with previous Ks/Vs
    #pragma unroll
    for (int it = 0; it < 8; ++it) {   // stage K tile [64 keys][256 c]
      const int idx = t + 256 * it;
      const int row = idx >> 5, ch = (idx & 31) * 8;
      *reinterpret_cast<short8v*>(&Ks[row][ch]) =
          *reinterpret_cast<const short8v*>(Kb + (size_t)(m0 + row) * C_ + ch);
    }
    #pragma unroll
    for (int it = 0; it < 8; ++it) {   // stage V tile [256 c][64 m]
      const int idx = t + 256 * it;
      const int c = idx >> 3, ch = (idx & 7) * 8;
      *reinterpret_cast<short8v*>(&Vs[c][ch]) =
          *reinterpret_cast<const short8v*>(Vb + (size_t)c * NTOK + m0 + ch);
    }
    __syncthreads();

    // ---- S = Q K^T : 4 n-tiles x 8 k-steps ----
    float4v sacc[4];
    #pragma unroll
    for (int nt = 0; nt < 4; ++nt) {
      sacc[nt] = (float4v){0.f, 0.f, 0.f, 0.f};
      #pragma unroll
      for (int kk = 0; kk < 8; ++kk) {
        short8v kf = *reinterpret_cast<const short8v*>(&Ks[nt * 16 + ln][kk * 32 + 8 * lg]);
        sacc[nt] = mfma16(qf[kk], kf, sacc[nt]);
      }
    }

    // ---- online softmax (row q = 4*lg + r lives in 16 lanes sharing lg) ----
    float alpha[4];
    #pragma unroll
    for (int r = 0; r < 4; ++r) {
      float mx = fmaxf(fmaxf(sacc[0][r], sacc[1][r]), fmaxf(sacc[2][r], sacc[3][r]));
      #pragma unroll
      for (int msk = 8; msk >= 1; msk >>= 1) mx = fmaxf(mx, __shfl_xor(mx, msk));
      const float mnew = fmaxf(m_run[r], mx);
      alpha[r] = __expf(m_run[r] - mnew);
      float ps = 0.f;
      #pragma unroll
      for (int nt = 0; nt < 4; ++nt) {
        const float p = __expf(sacc[nt][r] - mnew);
        sacc[nt][r] = p; ps += p;
      }
      #pragma unroll
      for (int msk = 8; msk >= 1; msk >>= 1) ps += __shfl_xor(ps, msk);
      l_run[r] = l_run[r] * alpha[r] + ps;
      m_run[r] = mnew;
    }
    // P -> LDS (bf16), own-wave only
    #pragma unroll
    for (int nt = 0; nt < 4; ++nt)
      #pragma unroll
      for (int r = 0; r < 4; ++r)
        Ps[w][4 * lg + r][nt * 16 + ln] = f2bf(sacc[nt][r]);
    // rescale O
    #pragma unroll
    for (int ct = 0; ct < 16; ++ct) {
      #pragma unroll
      for (int r = 0; r < 4; ++r) Oacc[ct][r] *= alpha[r];
    }
    // ---- PV: 16 c-tiles x 2 k-steps ----
    short8v pa0 = *reinterpret_cast<const short8v*>(&Ps[w][ln][8 * lg]);
    short8v pa1 = *reinterpret_cast<const short8v*>(&Ps[w][ln][32 + 8 * lg]);
    #pragma unroll
    for (int ct = 0; ct < 16; ++ct) {
      short8v vf0 = *reinterpret_cast<const short8v*>(&Vs[ct * 16 + ln][8 * lg]);
      Oacc[ct] = mfma16(pa0, vf0, Oacc[ct]);
      short8v vf1 = *reinterpret_cast<const short8v*>(&Vs[ct * 16 + ln][32 + 8 * lg]);
      Oacc[ct] = mfma16(pa1, vf1, Oacc[ct]);
    }
  }

  float invl[4];
  #pragma unroll
  for (int r = 0; r < 4; ++r) invl[r] = 1.0f / l_run[r];
  #pragma unroll
  for (int ct = 0; ct < 16; ++ct)
    #pragma unroll
    for (int r = 0; r < 4; ++r)
      Ob[(size_t)(q0 + 16 * w + 4 * lg + r) * C_ + ct * 16 + ln] =
          f2bf(Oacc[ct][r] * invl[r]);
}

// ---------------------------------------------------------------------------
extern "C" void kernel_launch(void* const* d_in, const int* in_sizes, int n_in,
                              void* d_out, int out_size, void* d_ws, size_t ws_size,
                              hipStream_t stream) {
  (void)in_sizes; (void)n_in; (void)out_size; (void)ws_size;
  const float* x     = (const float*)d_in[0];
  const float* gamma = (const float*)d_in[1];
  const float* beta  = (const float*)d_in[2];
  const float* wq    = (const float*)d_in[3];
  const float* bq    = (const float*)d_in[4];
  const float* wk    = (const float*)d_in[5];
  const float* bk    = (const float*)d_in[6];
  const float* wv    = (const float*)d_in[7];
  const float* bv    = (const float*)d_in[8];
  const float* wo    = (const float*)d_in[9];
  const float* bo    = (const float*)d_in[10];
  float* out = (float*)d_out;

  ushort_t* ws16 = (ushort_t*)d_ws;
  const size_t SZ2 = (size_t)B_ * NTOK * C_;  // 4,194,304 bf16 elems = 8 MB

  ushort_t* Ht = ws16;                 // [b][n][c] bf16
  ushort_t* Qt = ws16 + SZ2;           // [b][n][c] bf16 (prescaled)
  ushort_t* Kt = ws16 + 2 * SZ2;       // [b][n][c] bf16
  ushort_t* Vb = ws16 + 3 * SZ2;       // [b][c][n] bf16
  ushort_t* Ot = ws16 + 4 * SZ2;       // [b][n][c] bf16
  ushort_t* Wb = ws16 + 5 * SZ2;       // [4][256][256] bf16
  float* stats = (float*)(ws16 + 5 * SZ2 + 4 * 65536);  // [b][32][2] f32

  gn_stats<<<dim3(B_ * GROUPS_), 256, 0, stream>>>(x, stats);
  gn_apply<<<dim3(NTOK / 64, B_), 256, 0, stream>>>(x, gamma, beta, stats, Ht);
  wconv<<<dim3(64, 4), 256, 0, stream>>>(wq, wk, wv, wo, Wb);

  dim3 gg(NTOK / 64, B_);
  nin_mfma<0><<<gg, 256, 0, stream>>>(Wb,             bq, Ht, nullptr, Qt, QSCALE);
  nin_mfma<0><<<gg, 256, 0, stream>>>(Wb + 65536,     bk, Ht, nullptr, Kt, 1.0f);
  nin_mfma<1><<<gg, 256, 0, stream>>>(Wb + 2 * 65536, bv, Ht, nullptr, Vb, 1.0f);

  flash_mfma<<<gg, 256, 0, stream>>>(Qt, Kt, Vb, Ot);

  nin_mfma<2><<<gg, 256, 0, stream>>>(Wb + 3 * 65536, bo, Ot, x, out, 1.0f);
}

// Round 3
// 201.512 us; speedup vs baseline: 16.9367x; 1.3414x over previous
//
#include <hip/hip_runtime.h>
#include <math.h>

#define B_      4
#define C_      256
#define NTOK    4096
#define GROUPS_ 32
#define CPG_    8
#define EPS_    1e-6f
#define QSCALE  0.0625f   // 1/sqrt(256), folded into Q projection output
#define NSEG    4
#define KSEG    (NTOK / NSEG)   // 1024 keys per segment
#define QB      128             // queries per flash block (4 waves x 32)

typedef __attribute__((ext_vector_type(8)))  short short8v;
typedef __attribute__((ext_vector_type(4)))  short short4v;
typedef __attribute__((ext_vector_type(4)))  float float4v;
typedef __attribute__((ext_vector_type(16))) float f32x16;
typedef __attribute__((ext_vector_type(4)))  unsigned short ushort4v;
typedef unsigned short ushort_t;

__device__ __forceinline__ ushort_t f2bf(float f) {
  union { float f; unsigned u; } v; v.f = f;
  unsigned r = (v.u + 0x7FFFu + ((v.u >> 16) & 1u)) >> 16;  // RNE
  return (ushort_t)r;
}
__device__ __forceinline__ float bf2f(ushort_t u) {
  union { unsigned u; float f; } v; v.u = ((unsigned)u) << 16; return v.f;
}

__device__ __forceinline__ float4v mfma16(short8v a, short8v b, float4v c) {
  return __builtin_amdgcn_mfma_f32_16x16x32_bf16(a, b, c, 0, 0, 0);
}
__device__ __forceinline__ f32x16 mfma32(short8v a, short8v b, f32x16 c) {
  return __builtin_amdgcn_mfma_f32_32x32x16_bf16(a, b, c, 0, 0, 0);
}

// ---------------------------------------------------------------------------
// GN pass 1: per-(b,group) mean / rstd
// ---------------------------------------------------------------------------
__global__ __launch_bounds__(256) void gn_stats(const float* __restrict__ x,
                                                float* __restrict__ stats) {
  const int bg = blockIdx.x;
  const size_t base = (size_t)bg * CPG_ * NTOK;
  const int t = threadIdx.x;
  float s = 0.f, s2 = 0.f;
  for (int i = t * 4; i < CPG_ * NTOK; i += 1024) {
    float4 v = *reinterpret_cast<const float4*>(x + base + i);
    s  += v.x + v.y + v.z + v.w;
    s2 += v.x * v.x + v.y * v.y + v.z * v.z + v.w * v.w;
  }
  #pragma unroll
  for (int m = 32; m >= 1; m >>= 1) { s += __shfl_xor(s, m); s2 += __shfl_xor(s2, m); }
  __shared__ float red[8];
  const int wv = t >> 6;
  if ((t & 63) == 0) { red[wv] = s; red[4 + wv] = s2; }
  __syncthreads();
  if (t == 0) {
    float ts  = red[0] + red[1] + red[2] + red[3];
    float ts2 = red[4] + red[5] + red[6] + red[7];
    const float inv_n = 1.0f / (float)(CPG_ * NTOK);
    float mu  = ts * inv_n;
    float var = ts2 * inv_n - mu * mu;
    stats[bg * 2]     = mu;
    stats[bg * 2 + 1] = rsqrtf(var + EPS_);
  }
}

// ---------------------------------------------------------------------------
// GN pass 2: normalize + affine, write Ht[b][n][c] bf16 (token-major)
// ---------------------------------------------------------------------------
__global__ __launch_bounds__(256) void gn_apply(
    const float* __restrict__ x, const float* __restrict__ gamma,
    const float* __restrict__ beta, const float* __restrict__ stats,
    ushort_t* __restrict__ Ht) {
  const int b  = blockIdx.y;
  const int n0 = blockIdx.x * 64;
  const int t  = threadIdx.x;
  __shared__ __align__(16) ushort_t Hs[64][264];
  const float* xb = x + (size_t)b * C_ * NTOK;
  #pragma unroll
  for (int it = 0; it < 16; ++it) {
    const int idx = t + 256 * it;
    const int c   = idx >> 4;
    const int ch  = (idx & 15) * 4;
    float4 v = *reinterpret_cast<const float4*>(xb + (size_t)c * NTOK + n0 + ch);
    const float mu = stats[(b * GROUPS_ + (c >> 3)) * 2];
    const float rs = stats[(b * GROUPS_ + (c >> 3)) * 2 + 1];
    const float ga = gamma[c] * rs;
    const float be = beta[c] - mu * ga;
    Hs[ch + 0][c] = f2bf(v.x * ga + be);
    Hs[ch + 1][c] = f2bf(v.y * ga + be);
    Hs[ch + 2][c] = f2bf(v.z * ga + be);
    Hs[ch + 3][c] = f2bf(v.w * ga + be);
  }
  __syncthreads();
  ushort_t* Hb = Ht + (size_t)b * NTOK * C_;
  #pragma unroll
  for (int it = 0; it < 8; ++it) {
    const int idx = t + 256 * it;
    const int row = idx >> 5;
    const int ch  = (idx & 31) * 8;
    *reinterpret_cast<short8v*>(Hb + (size_t)(n0 + row) * C_ + ch) =
        *reinterpret_cast<const short8v*>(&Hs[row][ch]);
  }
}

// ---------------------------------------------------------------------------
// Convert the 4 weight matrices to bf16 (contiguous [4][256][256])
// ---------------------------------------------------------------------------
__global__ __launch_bounds__(256) void wconv(
    const float* __restrict__ wq, const float* __restrict__ wk,
    const float* __restrict__ wv, const float* __restrict__ wo,
    ushort_t* __restrict__ Wb) {
  const int m = blockIdx.y;
  const float* srcs[4] = {wq, wk, wv, wo};
  const float* s = srcs[m];
  const int i = (blockIdx.x * 256 + threadIdx.x) * 4;
  float4 v = *reinterpret_cast<const float4*>(s + i);
  ushort4v o4 = {f2bf(v.x), f2bf(v.y), f2bf(v.z), f2bf(v.w)};
  *reinterpret_cast<ushort4v*>(Wb + (size_t)m * 65536 + i) = o4;
}

// ---------------------------------------------------------------------------
// MFMA 1x1-conv GEMM (16x16x32): D[m][n] = sum_c W[m][c] * Ht[n][c]
// MODE 0: bf16 out transposed [n][m], (acc+bias)*oscale   (Q, K)
// MODE 1: bf16 out natural [m][n]                          (V)
// MODE 2: f32 out natural [m][n] + bias + residual x       (final)
// ---------------------------------------------------------------------------
template <int MODE>
__global__ __launch_bounds__(256) void nin_mfma(
    const ushort_t* __restrict__ Wb, const float* __restrict__ bias,
    const ushort_t* __restrict__ Hin, const float* __restrict__ xres,
    void* __restrict__ outp, float oscale) {
  const int b  = blockIdx.y;
  const int n0 = blockIdx.x * 64;
  const int t  = threadIdx.x;
  const int w  = t >> 6, l = t & 63;
  const int lg = l >> 4, ln = l & 15;
  __shared__ __align__(16) ushort_t Hs[64][264];
  const ushort_t* Hb = Hin + (size_t)b * NTOK * C_;
  #pragma unroll
  for (int it = 0; it < 8; ++it) {
    const int idx = t + 256 * it;
    const int row = idx >> 5;
    const int ch  = (idx & 31) * 8;
    *reinterpret_cast<short8v*>(&Hs[row][ch]) =
        *reinterpret_cast<const short8v*>(Hb + (size_t)(n0 + row) * C_ + ch);
  }
  __syncthreads();

  float4v acc[4][4];
  #pragma unroll
  for (int mt = 0; mt < 4; ++mt)
    #pragma unroll
    for (int nt = 0; nt < 4; ++nt) acc[mt][nt] = (float4v){0.f, 0.f, 0.f, 0.f};

  const ushort_t* Wrow = Wb + (size_t)(64 * w + ln) * C_;
  #pragma unroll
  for (int kk = 0; kk < 8; ++kk) {
    short8v af[4], bfr[4];
    #pragma unroll
    for (int mt = 0; mt < 4; ++mt)
      af[mt] = *reinterpret_cast<const short8v*>(Wrow + mt * 16 * C_ + kk * 32 + 8 * lg);
    #pragma unroll
    for (int nt = 0; nt < 4; ++nt)
      bfr[nt] = *reinterpret_cast<const short8v*>(&Hs[nt * 16 + ln][kk * 32 + 8 * lg]);
    #pragma unroll
    for (int mt = 0; mt < 4; ++mt)
      #pragma unroll
      for (int nt = 0; nt < 4; ++nt)
        acc[mt][nt] = mfma16(af[mt], bfr[nt], acc[mt][nt]);
  }

  #pragma unroll
  for (int mt = 0; mt < 4; ++mt) {
    const int mb = 64 * w + mt * 16 + 4 * lg;
    #pragma unroll
    for (int nt = 0; nt < 4; ++nt) {
      const int n = n0 + nt * 16 + ln;
      if (MODE == 0) {
        ushort4v pk;
        #pragma unroll
        for (int r = 0; r < 4; ++r)
          pk[r] = f2bf((acc[mt][nt][r] + bias[mb + r]) * oscale);
        *reinterpret_cast<ushort4v*>((ushort_t*)outp + ((size_t)b * NTOK + n) * C_ + mb) = pk;
      } else if (MODE == 1) {
        #pragma unroll
        for (int r = 0; r < 4; ++r)
          ((ushort_t*)outp)[((size_t)b * C_ + mb + r) * NTOK + n] =
              f2bf(acc[mt][nt][r] + bias[mb + r]);
      } else {
        #pragma unroll
        for (int r = 0; r < 4; ++r) {
          const size_t off = ((size_t)b * C_ + mb + r) * NTOK + n;
          ((float*)outp)[off] = acc[mt][nt][r] + bias[mb + r] + xres[off];
        }
      }
    }
  }
}

// ---------------------------------------------------------------------------
// Flash attention, 32x32x16 MFMA, swapped QK^T (S^T = K x Q), KV-split.
// Block: 128 q (4 waves x 32), KBLK=32 keys/iter, segment = 1024 keys.
// Lane owns q = lane&31; P lives in-register (key = (r&3)+8*(r>>2)+4*hi).
// V staged with key-index bit2<->bit3 swizzle so P regs feed PV A directly.
// Writes raw (unnormalized) O partials + (m,l) per segment.
// ---------------------------------------------------------------------------
__global__ __launch_bounds__(256, 2) void flash2(
    const ushort_t* __restrict__ Qt, const ushort_t* __restrict__ Kt,
    const ushort_t* __restrict__ V, ushort_t* __restrict__ O0,
    ushort_t* __restrict__ Orest, float2* __restrict__ ml) {
  const int b   = blockIdx.z;
  const int seg = blockIdx.y;
  const int q0  = blockIdx.x * QB;
  const int t = threadIdx.x, w = t >> 6, l = t & 63;
  const int ln = l & 31, hi = l >> 5;

  __shared__ __align__(16) ushort_t Ks[32][264];  // [key][ch], stride 528B
  __shared__ __align__(16) ushort_t Vs[256][40];  // [ch][key'], stride 80B

  const ushort_t* Kb_ = Kt + (size_t)b * NTOK * C_;
  const ushort_t* Vb_ = V  + (size_t)b * C_ * NTOK;

  // Q fragments (B operand), resident: lane = q row q0+32w+ln, ch = 16kk+8hi+j
  short8v qf[16];
  {
    const ushort_t* qrow = Qt + ((size_t)b * NTOK + q0 + 32 * w + ln) * C_ + 8 * hi;
    #pragma unroll
    for (int kk = 0; kk < 16; ++kk)
      qf[kk] = *reinterpret_cast<const short8v*>(qrow + 16 * kk);
  }

  f32x16 Oacc[8];
  #pragma unroll
  for (int ct = 0; ct < 8; ++ct)
    #pragma unroll
    for (int r = 0; r < 16; ++r) Oacc[ct][r] = 0.f;
  float m_run = -1e30f, l_run = 0.f;

  for (int it = 0; it < KSEG / 32; ++it) {
    const int k0 = seg * KSEG + it * 32;
    __syncthreads();
    {  // stage K tile [32 keys][256 ch]
      const int row = t >> 3, gq = t & 7;
      const ushort_t* src = Kb_ + (size_t)(k0 + row) * C_ + gq * 8;
      #pragma unroll
      for (int j = 0; j < 4; ++j)
        *reinterpret_cast<short8v*>(&Ks[row][gq * 8 + j * 64]) =
            *reinterpret_cast<const short8v*>(src + j * 64);
    }
    {  // stage V tile [256 ch][32 keys], key' = bitswap23(key&15)
      const int gk = t & 3, c0 = t >> 2;
      const int kpa = 4 * (gk & 1) + 16 * (gk >> 1);
      #pragma unroll
      for (int j = 0; j < 4; ++j) {
        const int c = c0 + 64 * j;
        short8v v8 = *reinterpret_cast<const short8v*>(
            Vb_ + (size_t)c * NTOK + k0 + 8 * gk);
        short4v lo4 = {v8[0], v8[1], v8[2], v8[3]};
        short4v hi4 = {v8[4], v8[5], v8[6], v8[7]};
        *reinterpret_cast<short4v*>(&Vs[c][kpa])     = lo4;
        *reinterpret_cast<short4v*>(&Vs[c][kpa + 8]) = hi4;
      }
    }
    __syncthreads();

    // ---- S^T = K x Q over 16 k-steps of 16 channels ----
    f32x16 sacc;
    #pragma unroll
    for (int r = 0; r < 16; ++r) sacc[r] = 0.f;
    #pragma unroll
    for (int kk = 0; kk < 16; ++kk) {
      short8v kf = *reinterpret_cast<const short8v*>(&Ks[ln][16 * kk + 8 * hi]);
      sacc = mfma32(kf, qf[kk], sacc);
    }

    // ---- online softmax; lane owns q = ln, 16 of 32 keys (hi-split) ----
    float pmax = sacc[0];
    #pragma unroll
    for (int r = 1; r < 16; ++r) pmax = fmaxf(pmax, sacc[r]);
    pmax = fmaxf(pmax, __shfl_xor(pmax, 32));
    if (!__all(pmax - m_run <= 8.0f)) {   // defer-max (T13)
      const float mnew = fmaxf(m_run, pmax);
      const float alpha = __expf(m_run - mnew);
      m_run = mnew;
      l_run *= alpha;
      float av[16];
      #pragma unroll
      for (int r = 0; r < 16; ++r)
        av[r] = __shfl(alpha, (r & 3) + 8 * (r >> 2) + 4 * hi);
      #pragma unroll
      for (int ct = 0; ct < 8; ++ct)
        #pragma unroll
        for (int r = 0; r < 16; ++r) Oacc[ct][r] *= av[r];
    }
    float ps = 0.f;
    #pragma unroll
    for (int r = 0; r < 16; ++r) {
      sacc[r] = __expf(sacc[r] - m_run);
      ps += sacc[r];
    }
    ps += __shfl_xor(ps, 32);
    l_run += ps;

    // ---- P (in-register) -> bf16 A-frags; PV ----
    short8v pa0, pa1;
    #pragma unroll
    for (int j = 0; j < 8; ++j) {
      pa0[j] = (short)f2bf(sacc[j]);
      pa1[j] = (short)f2bf(sacc[8 + j]);
    }
    #pragma unroll
    for (int ct = 0; ct < 8; ++ct) {
      const ushort_t* vrow = &Vs[32 * ct + ln][8 * hi];
      Oacc[ct] = mfma32(pa0, *reinterpret_cast<const short8v*>(vrow), Oacc[ct]);
      Oacc[ct] = mfma32(pa1, *reinterpret_cast<const short8v*>(vrow + 16), Oacc[ct]);
    }
  }

  // ---- epilogue: raw partials + (m,l) ----
  ushort_t* Op = (seg == 0 ? O0 : Orest + (size_t)(seg - 1) * (size_t)B_ * NTOK * C_)
               + (size_t)b * NTOK * C_;
  #pragma unroll
  for (int ct = 0; ct < 8; ++ct)
    #pragma unroll
    for (int r = 0; r < 16; ++r) {
      const int qr = q0 + 32 * w + (r & 3) + 8 * (r >> 2) + 4 * hi;
      Op[(size_t)qr * C_ + 32 * ct + ln] = f2bf(Oacc[ct][r]);
    }
  if (hi == 0)
    ml[(seg * B_ + b) * NTOK + q0 + 32 * w + ln] = make_float2(m_run, l_run);
}

// ---------------------------------------------------------------------------
// Combine NSEG raw partials: O = sum_s e^{m_s-M} O_s / sum_s e^{m_s-M} l_s
// ---------------------------------------------------------------------------
__global__ __launch_bounds__(256) void combine_k(
    const ushort_t* __restrict__ O0, const ushort_t* __restrict__ Orest,
    const float2* __restrict__ ml, ushort_t* __restrict__ Ot) {
  const int idx = blockIdx.x * 256 + threadIdx.x;
  const int c8 = idx & 31;
  const int bq = idx >> 5;            // b*4096 + q
  const int b = bq >> 12, q = bq & (NTOK - 1);
  float m4[NSEG], l4[NSEG];
  float M = -1e30f;
  #pragma unroll
  for (int s = 0; s < NSEG; ++s) {
    float2 v = ml[(s * B_ + b) * NTOK + q];
    m4[s] = v.x; l4[s] = v.y;
    M = fmaxf(M, v.x);
  }
  float L = 0.f, wsc[NSEG];
  #pragma unroll
  for (int s = 0; s < NSEG; ++s) { wsc[s] = __expf(m4[s] - M); L += wsc[s] * l4[s]; }
  const float inv = 1.0f / L;
  float acc[8];
  #pragma unroll
  for (int j = 0; j < 8; ++j) acc[j] = 0.f;
  const size_t SLOT = (size_t)B_ * NTOK * C_;
  #pragma unroll
  for (int s = 0; s < NSEG; ++s) {
    const ushort_t* op = (s == 0 ? O0 : Orest + (size_t)(s - 1) * SLOT);
    short8v v = *reinterpret_cast<const short8v*>(op + (size_t)bq * C_ + 8 * c8);
    #pragma unroll
    for (int j = 0; j < 8; ++j) acc[j] += wsc[s] * bf2f((ushort_t)v[j]);
  }
  short8v o8;
  #pragma unroll
  for (int j = 0; j < 8; ++j) o8[j] = (short)f2bf(acc[j] * inv);
  *reinterpret_cast<short8v*>(Ot + (size_t)bq * C_ + 8 * c8) = o8;
}

// ---------------------------------------------------------------------------
extern "C" void kernel_launch(void* const* d_in, const int* in_sizes, int n_in,
                              void* d_out, int out_size, void* d_ws, size_t ws_size,
                              hipStream_t stream) {
  (void)in_sizes; (void)n_in; (void)out_size; (void)ws_size;
  const float* x     = (const float*)d_in[0];
  const float* gamma = (const float*)d_in[1];
  const float* beta  = (const float*)d_in[2];
  const float* wq    = (const float*)d_in[3];
  const float* bq    = (const float*)d_in[4];
  const float* wk    = (const float*)d_in[5];
  const float* bk    = (const float*)d_in[6];
  const float* wv    = (const float*)d_in[7];
  const float* bv    = (const float*)d_in[8];
  const float* wo    = (const float*)d_in[9];
  const float* bo    = (const float*)d_in[10];
  float* out = (float*)d_out;

  ushort_t* ws16 = (ushort_t*)d_ws;
  const size_t SLOT = (size_t)B_ * NTOK * C_;  // 4,194,304 elems = 8 MB bf16

  ushort_t* Ht  = ws16;                 // slot 0: H, later Opart seg 0
  ushort_t* Qt  = ws16 + SLOT;          // slot 1: Q, later combined Ot
  ushort_t* Kt  = ws16 + 2 * SLOT;      // slot 2
  ushort_t* Vb  = ws16 + 3 * SLOT;      // slot 3 ([c][n] layout)
  ushort_t* OpR = ws16 + 4 * SLOT;      // slots 4..6: Opart segs 1..3
  ushort_t* Op0 = Ht;                   // seg 0 partial (Ht is dead by then)
  ushort_t* Ot  = Qt;                   // combined O (Qt dead after flash)
  ushort_t* Wb  = ws16 + 7 * SLOT;      // [4][256][256] bf16
  float*  stats = (float*)(Wb + 4 * 65536);       // 256 f32
  float2* mlp   = (float2*)(stats + 256);         // [NSEG][B][N] (m,l)

  gn_stats<<<dim3(B_ * GROUPS_), 256, 0, stream>>>(x, stats);
  gn_apply<<<dim3(NTOK / 64, B_), 256, 0, stream>>>(x, gamma, beta, stats, Ht);
  wconv<<<dim3(64, 4), 256, 0, stream>>>(wq, wk, wv, wo, Wb);

  dim3 gg(NTOK / 64, B_);
  nin_mfma<0><<<gg, 256, 0, stream>>>(Wb,             bq, Ht, nullptr, Qt, QSCALE);
  nin_mfma<0><<<gg, 256, 0, stream>>>(Wb + 65536,     bk, Ht, nullptr, Kt, 1.0f);
  nin_mfma<1><<<gg, 256, 0, stream>>>(Wb + 2 * 65536, bv, Ht, nullptr, Vb, 1.0f);

  flash2<<<dim3(NTOK / QB, NSEG, B_), 256, 0, stream>>>(Qt, Kt, Vb, Op0, OpR, mlp);
  combine_k<<<dim3(B_ * NTOK * C_ / 8 / 256), 256, 0, stream>>>(Op0, OpR, mlp, Ot);

  nin_mfma<2><<<gg, 256, 0, stream>>>(Wb + 3 * 65536, bo, Ot, x, out, 1.0f);
}